// Round 4
// baseline (614.449 us; speedup 1.0000x reference)
//
#include <hip/hip_runtime.h>

// sLSTM cell, fused block-diagonal-matmul + gate epilogue for MI355X (gfx950).
//
//  1) (ws big enough) wpack: W{i,f,z,o} (8,256,256) fp32 -> bf16 hi/lo, transposed
//     to [head][gate*256+e][k] so MFMA B-fragments are contiguous-k loads.
//  2) nscan: flag = any(n != 0)   (reference's jnp.all(n==0) stabilizer branch).
//  3) main<PACKED>: per block: one head, 64 batch rows, 64 e-cols, all 4 gates.
//     GEMM K=256 in BK=32 steps, 16x16x32 bf16 MFMA, 3-term hi/lo split
//     (AhBh + AhBl + AlBh, ~2^-16 rel err), xLSTM pointwise epilogue in-register.
//     PACKED=false fallback (tiny ws): reads fp32 W directly + converts in-loop.

#define BATCH 4096
#define FEAT  2048
#define NHEAD 8
#define HDIM  256
#define BF_TOT (size_t)(BATCH * (size_t)FEAT)   // 8388608

#define BM  64
#define BNE 64
#define BK  32

typedef __attribute__((ext_vector_type(8))) short  short8;   // 8 x bf16
typedef __attribute__((ext_vector_type(4))) float  floatx4;  // MFMA accumulator

__device__ __forceinline__ unsigned short f2bf(float x) {
    union { float f; unsigned int u; } v; v.f = x;
    unsigned int u = v.u;
    return (unsigned short)((u + 0x7FFFu + ((u >> 16) & 1u)) >> 16);  // RNE
}
__device__ __forceinline__ float bf2f(unsigned short b) {
    union { unsigned int u; float f; } v; v.u = ((unsigned int)b) << 16;
    return v.f;
}

// ---------------------------------------------------------------------------
// Kernel 0: zero the stabilizer flag (graph-safe; no hipMemsetAsync risk)
// ---------------------------------------------------------------------------
__global__ void flag_zero_kernel(int* __restrict__ flag) {
    if (threadIdx.x == 0) *flag = 0;
}

// ---------------------------------------------------------------------------
// Kernel 1 (packed path only): W -> bf16 hi/lo, [head][gate*256+e][k]
// grid: 8 heads * 4 gates * 4 e-tiles * 4 k-tiles = 512 blocks, 256 threads
// ---------------------------------------------------------------------------
__global__ __launch_bounds__(256) void wpack_kernel(
    const float* __restrict__ Wi, const float* __restrict__ Wf,
    const float* __restrict__ Wz, const float* __restrict__ Wo,
    unsigned short* __restrict__ Whi, unsigned short* __restrict__ Wlo)
{
    __shared__ float tile[64][65];
    int bid = blockIdx.x;
    int h  = bid >> 6;
    int g  = (bid >> 4) & 3;
    int et = (bid >> 2) & 3;
    int kt = bid & 3;
    const float* W = (g == 0 ? Wi : g == 1 ? Wf : g == 2 ? Wz : Wo) + (size_t)h * HDIM * HDIM;

    int t  = threadIdx.x;
    int rr = t >> 4;
    int cc = (t & 15) << 2;
#pragma unroll
    for (int p = 0; p < 4; ++p) {
        int r = p * 16 + rr;
        const float4 v = *(const float4*)(&W[(size_t)(kt * 64 + r) * HDIM + et * 64 + cc]);
        tile[r][cc + 0] = v.x; tile[r][cc + 1] = v.y;
        tile[r][cc + 2] = v.z; tile[r][cc + 3] = v.w;
    }
    __syncthreads();

    int er2 = t >> 3;
    int kc  = (t & 7) << 3;
#pragma unroll
    for (int p = 0; p < 2; ++p) {
        int er = p * 32 + er2;
        __align__(16) unsigned short hi8[8], lo8[8];
#pragma unroll
        for (int j = 0; j < 8; ++j) {
            float x = tile[kc + j][er];
            unsigned short hb = f2bf(x);
            hi8[j] = hb;
            lo8[j] = f2bf(x - bf2f(hb));
        }
        size_t o = ((size_t)((h * 4 + g) * 256 + et * 64 + er)) * HDIM + kt * 64 + kc;
        *(uint4*)(&Whi[o]) = *(const uint4*)hi8;
        *(uint4*)(&Wlo[o]) = *(const uint4*)lo8;
    }
}

// ---------------------------------------------------------------------------
// Kernel 2: flag = any(n != 0)
// ---------------------------------------------------------------------------
__global__ __launch_bounds__(256) void nscan_kernel(const float* __restrict__ n,
                                                    int* __restrict__ flag)
{
    size_t stride = (size_t)gridDim.x * blockDim.x;
    size_t i = (size_t)blockIdx.x * blockDim.x + threadIdx.x;
    bool nz = false;
    for (; i < BF_TOT / 4; i += stride) {
        float4 v = ((const float4*)n)[i];
        nz |= (v.x != 0.f) | (v.y != 0.f) | (v.z != 0.f) | (v.w != 0.f);
    }
    if (__any(nz) && (threadIdx.x & 63) == 0) atomicOr(flag, 1);
}

// ---------------------------------------------------------------------------
// Kernel 3: fused GEMM + epilogue. 256 threads = 4 waves; wave w owns e-cols
// [w*16, w*16+16), all 4 gates, all 64 batch rows.
// ---------------------------------------------------------------------------
template <bool PACKED>
__global__ __launch_bounds__(256) void slstm_main(
    const float* __restrict__ ig,  const float* __restrict__ fg,
    const float* __restrict__ zg,  const float* __restrict__ og,
    const float* __restrict__ cin, const float* __restrict__ nin,
    const float* __restrict__ mIn, const float* __restrict__ h,
    const float* __restrict__ bi,  const float* __restrict__ bfv,
    const float* __restrict__ bz,  const float* __restrict__ bo,
    const unsigned short* __restrict__ Whi, const unsigned short* __restrict__ Wlo,
    const float* __restrict__ W0, const float* __restrict__ W1,
    const float* __restrict__ W2, const float* __restrict__ W3,
    const int* __restrict__ flag, float* __restrict__ out)
{
    __shared__ __align__(16) unsigned short Ahi[BM * BK], Alo[BM * BK];
    __shared__ __align__(16) unsigned short Bhi[256 * BK], Blo[256 * BK];

    // XCD swizzle: 2048 blocks, 2048%8==0 -> bijective; one head per XCD
    int bid = blockIdx.x;
    int swz = (bid & 7) * 256 + (bid >> 3);
    int head = swz >> 8;
    int rem  = swz & 255;
    int m0 = (rem >> 2) * BM;
    int e0 = (rem & 3) * BNE;

    int t    = threadIdx.x;
    int lane = t & 63;
    int wave = t >> 6;
    int q    = lane >> 4;
    int cl   = lane & 15;

    floatx4 acc[4][4];
#pragma unroll
    for (int g2 = 0; g2 < 4; ++g2)
#pragma unroll
        for (int mf = 0; mf < 4; ++mf) acc[g2][mf] = (floatx4){0.f, 0.f, 0.f, 0.f};

    int ar = t >> 2;
    int ac = (t & 3) << 3;
    const float* hrow = h + (size_t)(m0 + ar) * FEAT + head * HDIM;

    for (int kt = 0; kt < 8; ++kt) {
        int k0 = kt * BK;
        // ---- global loads (issued before the barrier; overlap prev MFMA) ----
        float4 a0 = *(const float4*)(&hrow[k0 + ac]);
        float4 a1 = *(const float4*)(&hrow[k0 + ac + 4]);
        uint4 bhv[4], blv[4];
        float fw[4][8];
#pragma unroll
        for (int p = 0; p < 4; ++p) {
            int gid = p * 256 + t;
            int rb  = gid >> 2;          // 0..255 = gate*64 + ee
            int gr  = gid & 3;           // k-granule
            if (PACKED) {
                size_t widx = ((size_t)(head * 1024 + (rb >> 6) * 256 + e0 + (rb & 63))) * HDIM
                              + k0 + gr * 8;
                bhv[p] = *(const uint4*)(&Whi[widx]);
                blv[p] = *(const uint4*)(&Wlo[widx]);
            } else {
                int gate = rb >> 6;
                const float* Wg = (gate == 0 ? W0 : gate == 1 ? W1 : gate == 2 ? W2 : W3)
                                  + (size_t)head * HDIM * HDIM;
                int e = e0 + (rb & 63);
#pragma unroll
                for (int j = 0; j < 8; ++j)
                    fw[p][j] = Wg[(size_t)(k0 + gr * 8 + j) * HDIM + e];
            }
        }
        __syncthreads();   // previous iteration's fragment reads complete

        // ---- A: fp32 -> bf16 hi/lo split, swizzled ds_write_b128 ----
        {
            __align__(16) unsigned short hi8[8], lo8[8];
            float xs[8] = {a0.x, a0.y, a0.z, a0.w, a1.x, a1.y, a1.z, a1.w};
#pragma unroll
            for (int j = 0; j < 8; ++j) {
                unsigned short hb = f2bf(xs[j]);
                hi8[j] = hb;
                lo8[j] = f2bf(xs[j] - bf2f(hb));
            }
            int gr  = t & 3;
            int off = ar * BK + ((gr ^ (ar & 3)) << 3);
            *(uint4*)(&Ahi[off]) = *(const uint4*)hi8;
            *(uint4*)(&Alo[off]) = *(const uint4*)lo8;
        }
        // ---- B: swizzled ds_write_b128 ----
#pragma unroll
        for (int p = 0; p < 4; ++p) {
            int gid = p * 256 + t;
            int rb  = gid >> 2;
            int gr  = gid & 3;
            int off = rb * BK + ((gr ^ (rb & 3)) << 3);
            if (PACKED) {
                *(uint4*)(&Bhi[off]) = bhv[p];
                *(uint4*)(&Blo[off]) = blv[p];
            } else {
                __align__(16) unsigned short hi8[8], lo8[8];
#pragma unroll
                for (int j = 0; j < 8; ++j) {
                    unsigned short hb = f2bf(fw[p][j]);
                    hi8[j] = hb;
                    lo8[j] = f2bf(fw[p][j] - bf2f(hb));
                }
                *(uint4*)(&Bhi[off]) = *(const uint4*)hi8;
                *(uint4*)(&Blo[off]) = *(const uint4*)lo8;
            }
        }
        __syncthreads();   // tile ready

        // ---- fragments + MFMA: 48 mfma / 16 ds_read_b128 per wave ----
        short8 ah[4], al[4];
#pragma unroll
        for (int mf = 0; mf < 4; ++mf) {
            int row = mf * 16 + cl;
            int off = row * BK + ((q ^ (row & 3)) << 3);
            ah[mf] = *(const short8*)(&Ahi[off]);
            al[mf] = *(const short8*)(&Alo[off]);
        }
#pragma unroll
        for (int g2 = 0; g2 < 4; ++g2) {
            int rb  = g2 * 64 + wave * 16 + cl;
            int off = rb * BK + ((q ^ (rb & 3)) << 3);
            short8 bh = *(const short8*)(&Bhi[off]);
            short8 bl = *(const short8*)(&Blo[off]);
#pragma unroll
            for (int mf = 0; mf < 4; ++mf) {
                acc[g2][mf] = __builtin_amdgcn_mfma_f32_16x16x32_bf16(ah[mf], bh, acc[g2][mf], 0, 0, 0);
                acc[g2][mf] = __builtin_amdgcn_mfma_f32_16x16x32_bf16(ah[mf], bl, acc[g2][mf], 0, 0, 0);
                acc[g2][mf] = __builtin_amdgcn_mfma_f32_16x16x32_bf16(al[mf], bh, acc[g2][mf], 0, 0, 0);
            }
        }
    }

    // ---- epilogue: C/D layout col=lane&15, row=(lane>>4)*4+j  [m89-verified] ----
    int ecol = e0 + wave * 16 + cl;
    int fcol = head * HDIM + ecol;
    float vbi = bi[fcol], vbf = bfv[fcol], vbz = bz[fcol], vbo = bo[fcol];
    bool allz = (*flag == 0);

#pragma unroll
    for (int mf = 0; mf < 4; ++mf) {
#pragma unroll
        for (int j = 0; j < 4; ++j) {
            int brow = m0 + mf * 16 + q * 4 + j;
            size_t idx = (size_t)brow * FEAT + fcol;

            float ip  = ig[idx] + acc[0][mf][j] + vbi;
            float fp_ = fg[idx] + acc[1][mf][j] + vbf;
            float zp  = zg[idx] + acc[2][mf][j] + vbz;
            float op  = og[idx] + acc[3][mf][j] + vbo;

            float o_ = 1.f / (1.f + __expf(-op));
            float lf = (fp_ > 0.f) ? -log1pf(__expf(-fp_))
                                   : (fp_ - log1pf(__expf(fp_)));
            float mo = mIn[idx];
            float mn = allz ? ip : fmaxf(lf + mo, ip);
            float i_p = fminf(__expf(ip - mn), 1.f);
            float f_p = fminf(__expf(lf + mo - mn), 1.f);
            float th  = 1.f - 2.f / (__expf(2.f * zp) + 1.f);   // tanh
            float cn  = f_p * cin[idx] + i_p * th;
            float nn  = f_p * nin[idx] + i_p;
            float ht  = cn / fmaxf(nn, 1e-6f);
            float hn  = o_ * ht;

            out[idx]              = cn;
            out[BF_TOT + idx]     = nn;
            out[2 * BF_TOT + idx] = mn;
            out[3 * BF_TOT + idx] = hn;
            out[4 * BF_TOT + idx] = hn;
        }
    }
}

// ---------------------------------------------------------------------------
extern "C" void kernel_launch(void* const* d_in, const int* in_sizes, int n_in,
                              void* d_out, int out_size, void* d_ws, size_t ws_size,
                              hipStream_t stream)
{
    const float* ig  = (const float*)d_in[0];
    const float* fg  = (const float*)d_in[1];
    const float* zg  = (const float*)d_in[2];
    const float* og  = (const float*)d_in[3];
    const float* c_  = (const float*)d_in[4];
    const float* n_  = (const float*)d_in[5];
    const float* m_  = (const float*)d_in[6];
    const float* h_  = (const float*)d_in[7];
    const float* Wi  = (const float*)d_in[8];
    const float* Wf  = (const float*)d_in[9];
    const float* Wz  = (const float*)d_in[10];
    const float* Wo  = (const float*)d_in[11];
    const float* bi  = (const float*)d_in[12];
    const float* bf_ = (const float*)d_in[13];
    const float* bz  = (const float*)d_in[14];
    const float* bo  = (const float*)d_in[15];
    float* out = (float*)d_out;

    // ws layout: [0..1023] flag; Whi 4MB; Wlo 4MB  (packed path needs 8,389,632 B)
    const size_t WHALF = (size_t)NHEAD * 4 * 256 * 256 * 2;  // 4 MiB
    const size_t NEED  = 1024 + 2 * WHALF;
    int* flag = (int*)d_ws;
    unsigned short* Whi = (unsigned short*)((char*)d_ws + 1024);
    unsigned short* Wlo = (unsigned short*)((char*)d_ws + 1024 + WHALF);

    flag_zero_kernel<<<1, 64, 0, stream>>>(flag);
    nscan_kernel<<<512, 256, 0, stream>>>(n_, flag);

    if (ws_size >= NEED) {
        wpack_kernel<<<512, 256, 0, stream>>>(Wi, Wf, Wz, Wo, Whi, Wlo);
        slstm_main<true><<<2048, 256, 0, stream>>>(ig, fg, zg, og, c_, n_, m_, h_,
                                                   bi, bf_, bz, bo, Whi, Wlo,
                                                   nullptr, nullptr, nullptr, nullptr,
                                                   flag, out);
    } else {
        slstm_main<false><<<2048, 256, 0, stream>>>(ig, fg, zg, og, c_, n_, m_, h_,
                                                    bi, bf_, bz, bo, nullptr, nullptr,
                                                    Wi, Wf, Wz, Wo, flag, out);
    }
}

// Round 5
// 432.074 us; speedup vs baseline: 1.4221x; 1.4221x over previous
//
#include <hip/hip_runtime.h>

// sLSTM cell, fused block-diagonal-matmul + gate epilogue for MI355X (gfx950). v2
//
//  wpack2: W{i,f,z,o} (8,256,256) fp32 -> bf16 hi/lo packed in MFMA-fragment order:
//          granule16B[((head*4+et)*8+kt)*8 + g*2 + half][wave*64+lane]
//          so the main kernel loads B fragments DIRECTLY from global (L2-resident,
//          one coalesced 1KB dwordx4 load per wave per (gate,half)) — no B LDS.
//  nscan:  flag = any(n != 0)   (reference's jnp.all(n==0) stabilizer branch).
//  main:   per block: one head, 64 batch rows, 64 e-cols, 4 gates. K=256, BK=32,
//          16x16x32 bf16 MFMA, 3-term hi/lo split (AhBh+AhBl+AlBh, ~2^-16 rel).
//          A (h rows) staged via double-buffered swizzled LDS, 1 barrier/K-step.
//          Epilogue: acc -> LDS transpose (chunk-XOR swizzle) -> full-line float4
//          loads of ig/fg/zg/og/c/n/m and full-line float4 stores of 5 outputs.
//  Fallback (tiny ws): previous round's verified-correct kernel, W fp32 direct.

#define BATCH 4096
#define FEAT  2048
#define NHEAD 8
#define HDIM  256
#define BF_TOT (size_t)(BATCH * (size_t)FEAT)   // 8388608

#define BM  64
#define BK  32

typedef __attribute__((ext_vector_type(8))) short  short8;   // 8 x bf16
typedef __attribute__((ext_vector_type(4))) float  floatx4;

__device__ __forceinline__ unsigned short f2bf(float x) {
    union { float f; unsigned int u; } v; v.f = x;
    unsigned int u = v.u;
    return (unsigned short)((u + 0x7FFFu + ((u >> 16) & 1u)) >> 16);  // RNE
}
__device__ __forceinline__ float bf2f(unsigned short b) {
    union { unsigned int u; float f; } v; v.u = ((unsigned int)b) << 16;
    return v.f;
}

__global__ void flag_zero_kernel(int* __restrict__ flag) {
    if (threadIdx.x == 0) *flag = 0;
}

// ---------------------------------------------------------------------------
// wpack2: one block per (head, et, kt) = 8*4*8 = 256 blocks; loops over 4 gates.
// Output granule (16B = 8 bf16): content[j] = W[h][kt*32 + (l>>4)*8 + j][et*64 + w*16 + (l&15)]
// at uint4 index ((bid*4 + g)*2 + half)*256 + w*64 + l,  bid = (h*4+et)*8+kt.
// Block 0 also zeroes the flag (nscan launches strictly after).
// ---------------------------------------------------------------------------
__global__ __launch_bounds__(256) void wpack2_kernel(
    const float* __restrict__ Wi, const float* __restrict__ Wf,
    const float* __restrict__ Wz, const float* __restrict__ Wo,
    uint4* __restrict__ Wpk, int* __restrict__ flag)
{
    if (blockIdx.x == 0 && threadIdx.x == 0) *flag = 0;

    __shared__ float tile[32][68];   // 68: float4-aligned rows, banks spread on col-gather
    int bid = blockIdx.x;
    int h  = bid >> 5;          // 0..7
    int et = (bid >> 3) & 3;    // 0..3
    int kt = bid & 7;           // 0..7

    int t  = threadIdx.x;
    int r  = t >> 3;            // 0..31 (k-row in tile)
    int c0 = (t & 7) << 3;      // 0..56
    int w  = t >> 6;            // 0..3
    int l  = t & 63;
    int q  = l >> 4;
    int cl = l & 15;

    for (int g = 0; g < 4; ++g) {
        const float* W = (g == 0 ? Wi : g == 1 ? Wf : g == 2 ? Wz : Wo)
                         + (size_t)h * HDIM * HDIM;
        const float4 v0 = *(const float4*)(&W[(size_t)(kt * 32 + r) * HDIM + et * 64 + c0]);
        const float4 v1 = *(const float4*)(&W[(size_t)(kt * 32 + r) * HDIM + et * 64 + c0 + 4]);
        __syncthreads();  // protect previous gate's reads
        *(float4*)(&tile[r][c0])     = v0;
        *(float4*)(&tile[r][c0 + 4]) = v1;
        __syncthreads();

        __align__(16) unsigned short hi8[8], lo8[8];
#pragma unroll
        for (int j = 0; j < 8; ++j) {
            float x = tile[q * 8 + j][w * 16 + cl];
            unsigned short hb = f2bf(x);
            hi8[j] = hb;
            lo8[j] = f2bf(x - bf2f(hb));
        }
        size_t base = ((size_t)(bid * 4 + g) * 2) * 256 + w * 64 + l;
        Wpk[base]       = *(const uint4*)hi8;
        Wpk[base + 256] = *(const uint4*)lo8;
    }
}

// ---------------------------------------------------------------------------
// nscan: flag = any(n != 0)
// ---------------------------------------------------------------------------
__global__ __launch_bounds__(256) void nscan_kernel(const float* __restrict__ n,
                                                    int* __restrict__ flag)
{
    size_t stride = (size_t)gridDim.x * blockDim.x;
    size_t i = (size_t)blockIdx.x * blockDim.x + threadIdx.x;
    bool nz = false;
    for (; i < BF_TOT / 4; i += stride) {
        float4 v = ((const float4*)n)[i];
        nz |= (v.x != 0.f) | (v.y != 0.f) | (v.z != 0.f) | (v.w != 0.f);
    }
    if (__any(nz) && (threadIdx.x & 63) == 0) atomicOr(flag, 1);
}

// ---------------------------------------------------------------------------
// main v2: B direct-from-global (packed), A double-buffered LDS, LDS-transpose
// epilogue with full-line loads/stores.
// ---------------------------------------------------------------------------
__global__ __launch_bounds__(256, 3) void slstm_main2(
    const float* __restrict__ ig,  const float* __restrict__ fg,
    const float* __restrict__ zg,  const float* __restrict__ og,
    const float* __restrict__ cin, const float* __restrict__ nin,
    const float* __restrict__ mIn, const float* __restrict__ h,
    const float* __restrict__ bi,  const float* __restrict__ bfv,
    const float* __restrict__ bz,  const float* __restrict__ bo,
    const uint4* __restrict__ Wpk,
    const int* __restrict__ flag, float* __restrict__ out)
{
    __shared__ __align__(16) char smem[32768];
    unsigned short* Ah = (unsigned short*)smem;            // [2][2048] bf16 hi
    unsigned short* Al = (unsigned short*)(smem + 8192);   // [2][2048] bf16 lo
    float* S = (float*)smem;                               // epilogue tile [4][32][64]

    int bid = blockIdx.x;
    int swz = (bid & 7) * 256 + (bid >> 3);   // bijective (2048 % 8 == 0)
    int head = swz >> 8;                       // == bid & 7: one head per XCD
    int rem  = swz & 255;
    int m0 = (rem >> 2) * BM;
    int et = rem & 3;
    int e0 = et * 64;

    int t    = threadIdx.x;
    int lane = t & 63;
    int wave = t >> 6;
    int q    = lane >> 4;
    int cl   = lane & 15;

    floatx4 acc[4][4];
#pragma unroll
    for (int g2 = 0; g2 < 4; ++g2)
#pragma unroll
        for (int mf = 0; mf < 4; ++mf) acc[g2][mf] = (floatx4){0.f, 0.f, 0.f, 0.f};

    // A staging mapping
    int ar = t >> 2;
    int ac = (t & 3) << 3;
    int gr = t & 3;
    const float* hrow = h + (size_t)(m0 + ar) * FEAT + head * HDIM;
    int awoff = ar * BK + ((gr ^ (ar & 3)) << 3);   // swizzled write offset (elements)

    // B fragment base (uint4 granules): [((head*4+et)*8+kt)*8 + g2*2 + half]*256 + wave*64 + lane
    const uint4* wpBase = Wpk + ((size_t)((head * 4 + et) * 8) * 8) * 256 + wave * 64 + lane;

    // ---- prologue: stage A tile 0 into buf 0 ----
    {
        float4 a0 = *(const float4*)(&hrow[ac]);
        float4 a1 = *(const float4*)(&hrow[ac + 4]);
        __align__(16) unsigned short hi8[8], lo8[8];
        float xs[8] = {a0.x, a0.y, a0.z, a0.w, a1.x, a1.y, a1.z, a1.w};
#pragma unroll
        for (int j = 0; j < 8; ++j) {
            unsigned short hb = f2bf(xs[j]);
            hi8[j] = hb;
            lo8[j] = f2bf(xs[j] - bf2f(hb));
        }
        *(uint4*)(&Ah[awoff]) = *(const uint4*)hi8;
        *(uint4*)(&Al[awoff]) = *(const uint4*)lo8;
    }
    __syncthreads();

    for (int kt = 0; kt < 8; ++kt) {
        int cur = kt & 1;
        // ---- B fragment loads for this K-step: 8 coalesced dwordx4, L2-hit ----
        const uint4* wpB = wpBase + (size_t)kt * 2048;
        short8 bqh[4], bql[4];
#pragma unroll
        for (int g2 = 0; g2 < 4; ++g2) {
            bqh[g2] = *(const short8*)(wpB + g2 * 512);
            bql[g2] = *(const short8*)(wpB + g2 * 512 + 256);
        }
        // ---- A global loads for next K-step ----
        float4 a0, a1;
        if (kt < 7) {
            a0 = *(const float4*)(&hrow[(kt + 1) * BK + ac]);
            a1 = *(const float4*)(&hrow[(kt + 1) * BK + ac + 4]);
        }
        // ---- A fragment reads from current buffer ----
        short8 ah[4], al[4];
#pragma unroll
        for (int mf = 0; mf < 4; ++mf) {
            int row = mf * 16 + cl;
            int off = cur * 2048 + row * BK + ((q ^ (row & 3)) << 3);
            ah[mf] = *(const short8*)(&Ah[off]);
            al[mf] = *(const short8*)(&Al[off]);
        }
        // ---- stage A(kt+1) into other buffer ----
        if (kt < 7) {
            __align__(16) unsigned short hi8[8], lo8[8];
            float xs[8] = {a0.x, a0.y, a0.z, a0.w, a1.x, a1.y, a1.z, a1.w};
#pragma unroll
            for (int j = 0; j < 8; ++j) {
                unsigned short hb = f2bf(xs[j]);
                hi8[j] = hb;
                lo8[j] = f2bf(xs[j] - bf2f(hb));
            }
            int woff = (cur ^ 1) * 2048 + awoff;
            *(uint4*)(&Ah[woff]) = *(const uint4*)hi8;
            *(uint4*)(&Al[woff]) = *(const uint4*)lo8;
        }
        // ---- 48 MFMA ----
#pragma unroll
        for (int g2 = 0; g2 < 4; ++g2) {
            short8 bh = bqh[g2], bl = bql[g2];
#pragma unroll
            for (int mf = 0; mf < 4; ++mf) {
                acc[g2][mf] = __builtin_amdgcn_mfma_f32_16x16x32_bf16(ah[mf], bh, acc[g2][mf], 0, 0, 0);
                acc[g2][mf] = __builtin_amdgcn_mfma_f32_16x16x32_bf16(ah[mf], bl, acc[g2][mf], 0, 0, 0);
                acc[g2][mf] = __builtin_amdgcn_mfma_f32_16x16x32_bf16(al[mf], bh, acc[g2][mf], 0, 0, 0);
            }
        }
        __syncthreads();
    }

    // ---- epilogue: acc -> LDS transpose -> full-line loads/stores ----
    bool allz = (*flag == 0);
    int r2a = t >> 4;               // 0..15
    int c0  = (t & 15) << 2;        // 0..60 (4 consecutive cols)
    int fcol0 = head * HDIM + e0 + c0;
    floatx4 vbi = *(const floatx4*)&bi[fcol0];
    floatx4 vbf = *(const floatx4*)&bfv[fcol0];
    floatx4 vbz = *(const floatx4*)&bz[fcol0];
    floatx4 vbo = *(const floatx4*)&bo[fcol0];

#pragma unroll
    for (int hh = 0; hh < 2; ++hh) {
        __syncthreads();   // S overlaps A buffers (hh=0) / previous half (hh=1)
        // scatter acc for rows hh*32 .. hh*32+31
#pragma unroll
        for (int mm = 0; mm < 2; ++mm) {
            int mf = hh * 2 + mm;
#pragma unroll
            for (int g2 = 0; g2 < 4; ++g2)
#pragma unroll
                for (int j = 0; j < 4; ++j) {
                    int r = mm * 16 + q * 4 + j;                 // 0..31
                    int c = wave * 16 + cl;                      // 0..63
                    int cs = (c & 7) | (((((c >> 3) ^ r) & 7)) << 3);  // chunk-XOR
                    S[(g2 * 32 + r) * 64 + cs] = acc[g2][mf][j];
                }
        }
        __syncthreads();
        // gather + epilogue math + store: rows {r2a, r2a+16}, cols c0..c0+3
#pragma unroll
        for (int rr = 0; rr < 2; ++rr) {
            int r = r2a + rr * 16;
            int csw = ((((c0 >> 3) ^ r) & 7) << 3) | (c0 & 7);
            floatx4 iv = *(const floatx4*)&S[(0 * 32 + r) * 64 + csw];
            floatx4 fv = *(const floatx4*)&S[(1 * 32 + r) * 64 + csw];
            floatx4 zv = *(const floatx4*)&S[(2 * 32 + r) * 64 + csw];
            floatx4 ov = *(const floatx4*)&S[(3 * 32 + r) * 64 + csw];

            int brow = m0 + hh * 32 + r;
            size_t idx = (size_t)brow * FEAT + fcol0;

            floatx4 igv = *(const floatx4*)&ig[idx];
            floatx4 fgv = *(const floatx4*)&fg[idx];
            floatx4 zgv = *(const floatx4*)&zg[idx];
            floatx4 ogv = *(const floatx4*)&og[idx];
            floatx4 cv  = *(const floatx4*)&cin[idx];
            floatx4 nv  = *(const floatx4*)&nin[idx];
            floatx4 mv  = *(const floatx4*)&mIn[idx];

            floatx4 cnV, nnV, mnV, hnV;
#pragma unroll
            for (int e = 0; e < 4; ++e) {
                float ip  = igv[e] + iv[e] + vbi[e];
                float fp_ = fgv[e] + fv[e] + vbf[e];
                float zp  = zgv[e] + zv[e] + vbz[e];
                float op  = ogv[e] + ov[e] + vbo[e];

                float o_ = 1.f / (1.f + __expf(-op));
                float lf = (fp_ > 0.f) ? -log1pf(__expf(-fp_))
                                       : (fp_ - log1pf(__expf(fp_)));
                float mo = mv[e];
                float mn = allz ? ip : fmaxf(lf + mo, ip);
                float i_p = fminf(__expf(ip - mn), 1.f);
                float f_p = fminf(__expf(lf + mo - mn), 1.f);
                float th  = 1.f - 2.f / (__expf(2.f * zp) + 1.f);
                float cn  = f_p * cv[e] + i_p * th;
                float nn  = f_p * nv[e] + i_p;
                float ht  = cn / fmaxf(nn, 1e-6f);
                cnV[e] = cn; nnV[e] = nn; mnV[e] = mn; hnV[e] = o_ * ht;
            }
            *(floatx4*)&out[idx]              = cnV;
            *(floatx4*)&out[BF_TOT + idx]     = nnV;
            *(floatx4*)&out[2 * BF_TOT + idx] = mnV;
            *(floatx4*)&out[3 * BF_TOT + idx] = hnV;
            *(floatx4*)&out[4 * BF_TOT + idx] = hnV;
        }
    }
}

// ---------------------------------------------------------------------------
// Fallback (tiny ws): round-4 verified-correct kernel, fp32 W direct.
// ---------------------------------------------------------------------------
__global__ __launch_bounds__(256) void slstm_fb(
    const float* __restrict__ ig,  const float* __restrict__ fg,
    const float* __restrict__ zg,  const float* __restrict__ og,
    const float* __restrict__ cin, const float* __restrict__ nin,
    const float* __restrict__ mIn, const float* __restrict__ h,
    const float* __restrict__ bi,  const float* __restrict__ bfv,
    const float* __restrict__ bz,  const float* __restrict__ bo,
    const float* __restrict__ W0, const float* __restrict__ W1,
    const float* __restrict__ W2, const float* __restrict__ W3,
    const int* __restrict__ flag, float* __restrict__ out)
{
    __shared__ __align__(16) unsigned short Ahi[BM * BK], Alo[BM * BK];
    __shared__ __align__(16) unsigned short Bhi[256 * BK], Blo[256 * BK];

    int bid = blockIdx.x;
    int swz = (bid & 7) * 256 + (bid >> 3);
    int head = swz >> 8;
    int rem  = swz & 255;
    int m0 = (rem >> 2) * BM;
    int e0 = (rem & 3) * 64;

    int t    = threadIdx.x;
    int lane = t & 63;
    int wave = t >> 6;
    int q    = lane >> 4;
    int cl   = lane & 15;

    floatx4 acc[4][4];
#pragma unroll
    for (int g2 = 0; g2 < 4; ++g2)
#pragma unroll
        for (int mf = 0; mf < 4; ++mf) acc[g2][mf] = (floatx4){0.f, 0.f, 0.f, 0.f};

    int ar = t >> 2;
    int ac = (t & 3) << 3;
    const float* hrow = h + (size_t)(m0 + ar) * FEAT + head * HDIM;

    for (int kt = 0; kt < 8; ++kt) {
        int k0 = kt * BK;
        float4 a0 = *(const float4*)(&hrow[k0 + ac]);
        float4 a1 = *(const float4*)(&hrow[k0 + ac + 4]);
        float fw[4][8];
#pragma unroll
        for (int p = 0; p < 4; ++p) {
            int gid = p * 256 + t;
            int rb  = gid >> 2;
            int gr  = gid & 3;
            int gate = rb >> 6;
            const float* Wg = (gate == 0 ? W0 : gate == 1 ? W1 : gate == 2 ? W2 : W3)
                              + (size_t)head * HDIM * HDIM;
            int e = e0 + (rb & 63);
#pragma unroll
            for (int j = 0; j < 8; ++j)
                fw[p][j] = Wg[(size_t)(k0 + gr * 8 + j) * HDIM + e];
        }
        __syncthreads();
        {
            __align__(16) unsigned short hi8[8], lo8[8];
            float xs[8] = {a0.x, a0.y, a0.z, a0.w, a1.x, a1.y, a1.z, a1.w};
#pragma unroll
            for (int j = 0; j < 8; ++j) {
                unsigned short hb = f2bf(xs[j]);
                hi8[j] = hb;
                lo8[j] = f2bf(xs[j] - bf2f(hb));
            }
            int gr2 = t & 3;
            int off = ar * BK + ((gr2 ^ (ar & 3)) << 3);
            *(uint4*)(&Ahi[off]) = *(const uint4*)hi8;
            *(uint4*)(&Alo[off]) = *(const uint4*)lo8;
        }
#pragma unroll
        for (int p = 0; p < 4; ++p) {
            int gid = p * 256 + t;
            int rb  = gid >> 2;
            int gr2 = gid & 3;
            int off = rb * BK + ((gr2 ^ (rb & 3)) << 3);
            __align__(16) unsigned short hi8[8], lo8[8];
#pragma unroll
            for (int j = 0; j < 8; ++j) {
                unsigned short hb = f2bf(fw[p][j]);
                hi8[j] = hb;
                lo8[j] = f2bf(fw[p][j] - bf2f(hb));
            }
            *(uint4*)(&Bhi[off]) = *(const uint4*)hi8;
            *(uint4*)(&Blo[off]) = *(const uint4*)lo8;
        }
        __syncthreads();

        short8 ah[4], al[4];
#pragma unroll
        for (int mf = 0; mf < 4; ++mf) {
            int row = mf * 16 + cl;
            int off = row * BK + ((q ^ (row & 3)) << 3);
            ah[mf] = *(const short8*)(&Ahi[off]);
            al[mf] = *(const short8*)(&Alo[off]);
        }
#pragma unroll
        for (int g2 = 0; g2 < 4; ++g2) {
            int rb  = g2 * 64 + wave * 16 + cl;
            int off = rb * BK + ((q ^ (rb & 3)) << 3);
            short8 bh = *(const short8*)(&Bhi[off]);
            short8 bl = *(const short8*)(&Blo[off]);
#pragma unroll
            for (int mf = 0; mf < 4; ++mf) {
                acc[g2][mf] = __builtin_amdgcn_mfma_f32_16x16x32_bf16(ah[mf], bh, acc[g2][mf], 0, 0, 0);
                acc[g2][mf] = __builtin_amdgcn_mfma_f32_16x16x32_bf16(ah[mf], bl, acc[g2][mf], 0, 0, 0);
                acc[g2][mf] = __builtin_amdgcn_mfma_f32_16x16x32_bf16(al[mf], bh, acc[g2][mf], 0, 0, 0);
            }
        }
    }

    int ecol = e0 + wave * 16 + cl;
    int fcol = head * HDIM + ecol;
    float vbi = bi[fcol], vbf = bfv[fcol], vbz = bz[fcol], vbo = bo[fcol];
    bool allz = (*flag == 0);

#pragma unroll
    for (int mf = 0; mf < 4; ++mf) {
#pragma unroll
        for (int j = 0; j < 4; ++j) {
            int brow = m0 + mf * 16 + q * 4 + j;
            size_t idx = (size_t)brow * FEAT + fcol;

            float ip  = ig[idx] + acc[0][mf][j] + vbi;
            float fp_ = fg[idx] + acc[1][mf][j] + vbf;
            float zp  = zg[idx] + acc[2][mf][j] + vbz;
            float op  = og[idx] + acc[3][mf][j] + vbo;

            float o_ = 1.f / (1.f + __expf(-op));
            float lf = (fp_ > 0.f) ? -log1pf(__expf(-fp_))
                                   : (fp_ - log1pf(__expf(fp_)));
            float mo = mIn[idx];
            float mn = allz ? ip : fmaxf(lf + mo, ip);
            float i_p = fminf(__expf(ip - mn), 1.f);
            float f_p = fminf(__expf(lf + mo - mn), 1.f);
            float th  = 1.f - 2.f / (__expf(2.f * zp) + 1.f);
            float cn  = f_p * cin[idx] + i_p * th;
            float nn  = f_p * nin[idx] + i_p;
            float ht  = cn / fmaxf(nn, 1e-6f);
            float hn  = o_ * ht;

            out[idx]              = cn;
            out[BF_TOT + idx]     = nn;
            out[2 * BF_TOT + idx] = mn;
            out[3 * BF_TOT + idx] = hn;
            out[4 * BF_TOT + idx] = hn;
        }
    }
}

// ---------------------------------------------------------------------------
extern "C" void kernel_launch(void* const* d_in, const int* in_sizes, int n_in,
                              void* d_out, int out_size, void* d_ws, size_t ws_size,
                              hipStream_t stream)
{
    const float* ig  = (const float*)d_in[0];
    const float* fg  = (const float*)d_in[1];
    const float* zg  = (const float*)d_in[2];
    const float* og  = (const float*)d_in[3];
    const float* c_  = (const float*)d_in[4];
    const float* n_  = (const float*)d_in[5];
    const float* m_  = (const float*)d_in[6];
    const float* h_  = (const float*)d_in[7];
    const float* Wi  = (const float*)d_in[8];
    const float* Wf  = (const float*)d_in[9];
    const float* Wz  = (const float*)d_in[10];
    const float* Wo  = (const float*)d_in[11];
    const float* bi  = (const float*)d_in[12];
    const float* bf_ = (const float*)d_in[13];
    const float* bz  = (const float*)d_in[14];
    const float* bo  = (const float*)d_in[15];
    float* out = (float*)d_out;

    // ws: flag @0; Wpk (8 MiB) @1024
    const size_t WPK_BYTES = (size_t)8 * 4 * 8 * 4 * 2 * 256 * 16;  // 8 MiB
    const size_t NEED = 1024 + WPK_BYTES;
    int* flag = (int*)d_ws;
    uint4* Wpk = (uint4*)((char*)d_ws + 1024);

    if (ws_size >= NEED) {
        wpack2_kernel<<<256, 256, 0, stream>>>(Wi, Wf, Wz, Wo, Wpk, flag);
        nscan_kernel<<<512, 256, 0, stream>>>(n_, flag);
        slstm_main2<<<2048, 256, 0, stream>>>(ig, fg, zg, og, c_, n_, m_, h_,
                                              bi, bf_, bz, bo, Wpk, flag, out);
    } else {
        flag_zero_kernel<<<1, 64, 0, stream>>>(flag);
        nscan_kernel<<<512, 256, 0, stream>>>(n_, flag);
        slstm_fb<<<2048, 256, 0, stream>>>(ig, fg, zg, og, c_, n_, m_, h_,
                                           bi, bf_, bz, bo, Wi, Wf, Wz, Wo, flag, out);
    }
}